// Round 2
// baseline (108.531 us; speedup 1.0000x reference)
//
#include <hip/hip_runtime.h>
#include <hip/hip_bf16.h>

#define NROW 4096
#define D 128
#define TOT 8192  // 2N
// sqrt(2 * log2(e)) : fold temperature (/0.5) and ln->log2 into stored operand
#define PRESCALE 1.69864407f
#define GRID_G 1024
#define CPB 256   // cols per k_gemm block
#define NT 16     // 16-col tiles per block

typedef __attribute__((ext_vector_type(8))) short bf16x8;
typedef __attribute__((ext_vector_type(4))) float f32x4;

__device__ __forceinline__ float fast_exp2(float x) {
#if __has_builtin(__builtin_amdgcn_exp2f)
  return __builtin_amdgcn_exp2f(x);
#else
  return exp2f(x);
#endif
}
__device__ __forceinline__ float fast_log2(float x) {
#if __has_builtin(__builtin_amdgcn_logf)
  return __builtin_amdgcn_logf(x);
#else
  return log2f(x);
#endif
}

__device__ __forceinline__ unsigned short f2bf(float x) {
  unsigned u = __float_as_uint(x);
  unsigned r = (u + 0x7fffu + ((u >> 16) & 1u)) >> 16;
  return (unsigned short)r;
}

__device__ __forceinline__ void gload16(const void* g, void* l) {
  __builtin_amdgcn_global_load_lds(
      (const __attribute__((address_space(1))) unsigned int*)g,
      (__attribute__((address_space(3))) unsigned int*)l, 16, 0, 0);
}

// Kernel 1: normalize rows -> prescaled bf16 Z; exact fp32 pos logits;
// also zero rowsum and the completion counter (replaces memsets).
__global__ __launch_bounds__(256) void k_norm(
    const float* __restrict__ ei, const float* __restrict__ ej,
    unsigned short* __restrict__ Zp, float* __restrict__ pos,
    float* __restrict__ rowsum, unsigned* __restrict__ ctr) {
  int gid = blockIdx.x * 256 + (int)threadIdx.x;
  if (gid < TOT) rowsum[gid] = 0.0f;
  if (gid == TOT) *ctr = 0u;

  int wid = threadIdx.x >> 6;
  int lane = threadIdx.x & 63;
  int r = blockIdx.x * 4 + wid;
  const float2 xi = *(const float2*)(ei + (size_t)r * D + lane * 2);
  const float2 xj = *(const float2*)(ej + (size_t)r * D + lane * 2);
  float si = xi.x * xi.x + xi.y * xi.y;
  float sj = xj.x * xj.x + xj.y * xj.y;
  float dd = xi.x * xj.x + xi.y * xj.y;
#pragma unroll
  for (int m = 32; m >= 1; m >>= 1) {
    si += __shfl_xor(si, m, 64);
    sj += __shfl_xor(sj, m, 64);
    dd += __shfl_xor(dd, m, 64);
  }
  float ri = rsqrtf(si); ri = ri * (1.5f - 0.5f * si * ri * ri);
  float rj = rsqrtf(sj); rj = rj * (1.5f - 0.5f * sj * rj * rj);
  unsigned short a0 = f2bf(xi.x * ri * PRESCALE);
  unsigned short a1 = f2bf(xi.y * ri * PRESCALE);
  unsigned short b0 = f2bf(xj.x * rj * PRESCALE);
  unsigned short b1 = f2bf(xj.y * rj * PRESCALE);
  ((unsigned*)(Zp + (size_t)r * D))[lane] = (unsigned)a0 | ((unsigned)a1 << 16);
  ((unsigned*)(Zp + (size_t)(r + NROW) * D))[lane] = (unsigned)b0 | ((unsigned)b1 << 16);
  if (lane == 0) pos[r] = 2.0f * dd * ri * rj;
}

// Kernel 2: fused Z*Z^T + exp + row sums + (last block) final loss.
// Block: 256 rows x 256 cols, 4 waves x 64 rows. B tiles (16 cols) staged in
// LDS double-buffered via global_load_lds, XOR-swizzled, counted vmcnt.
// XCD-pinned col-slices: per-XCD working set 2.25 MB -> local-L2 resident.
__global__ __launch_bounds__(256, 4) void k_gemm(
    const unsigned short* __restrict__ Zp, float* __restrict__ rowsum,
    const float* __restrict__ pos, unsigned* __restrict__ ctr,
    float* __restrict__ out) {
  __shared__ __align__(16) char ldsb[8192];  // 2 x 4KB tile buffers
  const int tid = (int)threadIdx.x;
  const int wid = tid >> 6, lane = tid & 63;
  const int lo = lane & 15, hi = lane >> 4;
  const unsigned b = blockIdx.x;
  const int cs = (int)((b & 7u) * 4u + ((b >> 3) & 3u));  // col-slice, XCD-pinned
  const int rb = (int)(b >> 5);                           // row-group
  const int rowbase = rb * 256 + wid * 64;

  // A fragments: 64 rows x 128 k in registers (64 VGPR)
  bf16x8 af[4][4];
#pragma unroll
  for (int g = 0; g < 4; ++g) {
    const unsigned short* za = Zp + (size_t)(rowbase + g * 16 + lo) * D + hi * 8;
#pragma unroll
    for (int kk = 0; kk < 4; ++kk) af[g][kk] = *(const bf16x8*)(za + kk * 32);
  }

  // Swizzled LDS read offsets: row lo, byte (m*16) ^ ((lo&7)<<4), m=kk*4+hi
  int rdoff[4];
  const int sw = (lo & 7) << 4;
#pragma unroll
  for (int kk = 0; kk < 4; ++kk) rdoff[kk] = lo * 256 + (((kk * 4 + hi) * 16) ^ sw);

  // Pre-swizzled global staging source: lane writes LDS linear slot
  // (row Rr, byte B0); source byte = B0 ^ ((Rr&7)<<4) within the row.
  const int Rr = wid * 4 + (lane >> 4);
  const int B0 = (lane & 15) * 16;
  const char* gbase = (const char*)Zp + (size_t)cs * CPB * 256 +
                      (size_t)Rr * 256 + (size_t)(B0 ^ ((Rr & 7) << 4));
  char* ldsw = ldsb + wid * 1024;

  float sums[4][4];
#pragma unroll
  for (int g = 0; g < 4; ++g)
#pragma unroll
    for (int r = 0; r < 4; ++r) sums[g][r] = 0.0f;

  const bool blkdiag = (cs == rb);

  // prologue: stage tile 0; drain A-loads + stage(0) together
  gload16(gbase, ldsw);
  asm volatile("s_waitcnt vmcnt(0)" ::: "memory");

#pragma unroll 2
  for (int t = 0; t < NT; ++t) {
    if (t + 1 < NT) {
      gload16(gbase + (size_t)(t + 1) * 4096, ldsw + ((t + 1) & 1) * 4096);
      asm volatile("s_waitcnt vmcnt(1)" ::: "memory");  // tile t landed
    } else {
      asm volatile("s_waitcnt vmcnt(0)" ::: "memory");
    }
    __builtin_amdgcn_s_barrier();  // all waves' quarters of tile t landed

    const char* ldsr = ldsb + (t & 1) * 4096;
    f32x4 acc[4];
#pragma unroll
    for (int g = 0; g < 4; ++g) acc[g] = (f32x4){0.f, 0.f, 0.f, 0.f};
#pragma unroll
    for (int kk = 0; kk < 4; ++kk) {
      bf16x8 bfv = *(const bf16x8*)(ldsr + rdoff[kk]);
#pragma unroll
      for (int g = 0; g < 4; ++g)
        acc[g] = __builtin_amdgcn_mfma_f32_16x16x32_bf16(af[g][kk], bfv, acc[g], 0, 0, 0);
    }
    const int gd = blkdiag ? (t - wid * 4) : -1;
#pragma unroll
    for (int g = 0; g < 4; ++g)
#pragma unroll
      for (int r = 0; r < 4; ++r) {
        float e = fast_exp2(acc[g][r]);
        sums[g][r] += (g == gd && lo == hi * 4 + r) ? 0.0f : e;
      }
    asm volatile("s_waitcnt lgkmcnt(0)" ::: "memory");  // ds_reads of tile t done
    __builtin_amdgcn_sched_barrier(0);
    __builtin_amdgcn_s_barrier();  // safe to overwrite buf (t&1) next iter
  }

  // column-slot reduce, one atomic per row per wave
#pragma unroll
  for (int g = 0; g < 4; ++g)
#pragma unroll
    for (int r = 0; r < 4; ++r) {
      float v = sums[g][r];
      v += __shfl_xor(v, 1, 64);
      v += __shfl_xor(v, 2, 64);
      v += __shfl_xor(v, 4, 64);
      v += __shfl_xor(v, 8, 64);
      if (lo == 0) atomicAdd(&rowsum[rowbase + g * 16 + hi * 4 + r], v);
    }

  // last-block-done: fold the final reduction into this dispatch
  __syncthreads();  // drains each wave's outstanding atomics (vmcnt(0))
  __shared__ unsigned slast;
  if (tid == 0) {
    __threadfence();
    slast = atomicAdd(ctr, 1u);
  }
  __syncthreads();
  if (slast == GRID_G - 1) {
    float s1 = 0.0f, s2 = 0.0f;
    for (int k = tid; k < TOT; k += 256) {
      float v = __hip_atomic_load(&rowsum[k], __ATOMIC_RELAXED, __HIP_MEMORY_SCOPE_AGENT);
      s1 += fast_log2(v);
    }
    for (int k = tid; k < NROW; k += 256) s2 += pos[k];
    float c = s1 * (0.69314718055994531f / (float)TOT) - s2 * (1.0f / (float)NROW);
#pragma unroll
    for (int m = 32; m >= 1; m >>= 1) c += __shfl_xor(c, m, 64);
    __shared__ float wsum[4];
    if (lane == 0) wsum[wid] = c;
    __syncthreads();
    if (tid == 0) out[0] = wsum[0] + wsum[1] + wsum[2] + wsum[3];
  }
}

extern "C" void kernel_launch(void* const* d_in, const int* in_sizes, int n_in,
                              void* d_out, int out_size, void* d_ws, size_t ws_size,
                              hipStream_t stream) {
  const float* ei = (const float*)d_in[0];
  const float* ej = (const float*)d_in[1];
  float* out = (float*)d_out;
  float* rowsum = (float*)d_ws;                                  // 8192 f32
  float* pos = (float*)((char*)d_ws + TOT * 4);                  // 4096 f32
  unsigned* ctr = (unsigned*)((char*)d_ws + TOT * 4 + NROW * 4); // 1 u32
  unsigned short* Zp =
      (unsigned short*)((char*)d_ws + TOT * 4 + NROW * 4 + 256); // 8192x128 bf16

  k_norm<<<NROW / 4, 256, 0, stream>>>(ei, ej, Zp, pos, rowsum, ctr);
  k_gemm<<<GRID_G, 256, 0, stream>>>(Zp, rowsum, pos, ctr, out);
}